// Round 7
// baseline (35.990 us; speedup 1.0000x reference)
//
#include <hip/hip_runtime.h>
#include <math.h>

#define UNITS 4096
#define BLK 256
#define CHUNKS 4      // 256 threads * 4 chunks * 4 floats = 4096 per row
#define NBINS 1024

typedef float f32x4 __attribute__((ext_vector_type(4)));

__device__ __forceinline__ void nt_store4(float4* p, float4 v) {
  __builtin_nontemporal_store(*reinterpret_cast<f32x4*>(&v),
                              reinterpret_cast<f32x4*>(p));
}

__global__ __launch_bounds__(BLK) void srp_kernel(
    const float* __restrict__ pw, const float* __restrict__ bs,
    const float* __restrict__ msk, const float* __restrict__ budget,
    const float* __restrict__ prev, const int* __restrict__ cf,
    float* __restrict__ out, int nrows) {
  constexpr float TOPK_RATIO = 0.35f;
  constexpr float MIN_BW = 0.1f;
  constexpr float BIAS_W = 0.15f;
  constexpr float TEMP = 0.12f;
  constexpr float EPSF = 1e-6f;
  constexpr float HIV = 1.25f;  // scores <= 1.165 < 1.25
  const float binscale = (float)NBINS / HIV;

  __shared__ int s_h0[NBINS];   // 4 KB, block-shared (row 0)
  __shared__ int s_h1[NBINS];   // 4 KB, block-shared (row 1)
  __shared__ int s_w0[4], s_w1[4];
  __shared__ int s_bin0, s_bin1;
  __shared__ float s_part[16];

  const int tid = threadIdx.x;
  const int lane = tid & 63;
  const int wid = tid >> 6;
  const int row0 = blockIdx.x * 2;
  const int row1 = row0 + 1;
  const bool valid1 = (row1 < nrows);
  const size_t base0 = (size_t)row0 * UNITS;
  const size_t base1 = (size_t)row1 * UNITS;

  reinterpret_cast<int4*>(s_h0)[tid] = make_int4(0, 0, 0, 0);
  reinterpret_cast<int4*>(s_h1)[tid] = make_int4(0, 0, 0, 0);

  int vf0 = cf[row0];
  const float bud0 = budget[row0];
  int vf1 = valid1 ? cf[row1] : 0;
  const float bud1 = valid1 ? budget[row1] : 0.0f;

  // ---- narrow 3-round ballot probes, both rows interleaved:
  // lanes 0-7 probe row0, lanes 32-39 probe row1 (prefix-of-ones mask).
  bool t1 = false;
  if (lane < 8) t1 = msk[base0 + lane * 512 + 511] > 0.0f;
  else if (valid1 && lane >= 32 && lane < 40)
    t1 = msk[base1 + (size_t)(lane - 32) * 512 + 511] > 0.0f;
  const unsigned long long b1m = __ballot(t1);
  const int q1_0 = __popcll(b1m & 0xFFull);
  const int q1_1 = __popcll((b1m >> 32) & 0xFFull);

  bool t2 = false;
  if (lane < 8 && q1_0 < 8) t2 = msk[base0 + q1_0 * 512 + lane * 64 + 63] > 0.0f;
  else if (valid1 && lane >= 32 && lane < 40 && q1_1 < 8)
    t2 = msk[base1 + q1_1 * 512 + (lane - 32) * 64 + 63] > 0.0f;
  const unsigned long long b2m = __ballot(t2);
  const int q2_0 = __popcll(b2m & 0xFFull);
  const int q2_1 = __popcll((b2m >> 32) & 0xFFull);

  const int q0_0 = q1_0 * 512 + q2_0 * 64;
  const int q0_1 = q1_1 * 512 + q2_1 * 64;
  const float r3a = (q1_0 < 8) ? msk[base0 + q0_0 + lane] : 0.0f;
  const float r3b = (valid1 && q1_1 < 8) ? msk[base1 + q0_1 + lane] : 0.0f;
  const int L0 = (q1_0 == 8) ? 4096 : q0_0 + __popcll(__ballot(r3a > 0.0f));
  const int L1 = !valid1 ? 0
                         : ((q1_1 == 8) ? 4096 : q0_1 + __popcll(__ballot(r3b > 0.0f)));

  // per-row top-k params
  float kf0 = fmaxf(1.0f, rintf((float)L0 * TOPK_RATIO));  // rintf == jnp.round
  kf0 = fminf(kf0, fmaxf((float)L0, 1.0f));
  const int kk0 = (int)kf0;
  const bool ng0 = (kf0 >= (float)L0);
  vf0 = min(max(vf0, 0), UNITS);
  const int vfL0 = min(vf0, L0);

  float kf1 = fmaxf(1.0f, rintf((float)L1 * TOPK_RATIO));
  kf1 = fminf(kf1, fmaxf((float)L1, 1.0f));
  const int kk1 = (int)kf1;
  const bool ng1 = valid1 ? (kf1 >= (float)L1) : true;
  vf1 = min(max(vf1, 0), UNITS);
  const int vfL1 = min(vf1, L1);

  const float4* pw40 = reinterpret_cast<const float4*>(pw + base0);
  const float4* bs40 = reinterpret_cast<const float4*>(bs + base0);
  const float4* pv40 = reinterpret_cast<const float4*>(prev + base0);
  float4* out40 = reinterpret_cast<float4*>(out + base0);
  const float4* pw41 = reinterpret_cast<const float4*>(pw + base1);
  const float4* bs41 = reinterpret_cast<const float4*>(bs + base1);
  const float4* pv41 = reinterpret_cast<const float4*>(prev + base1);
  float4* out41 = reinterpret_cast<float4*>(out + base1);
  const float4 zero4 = make_float4(0.f, 0.f, 0.f, 0.f);

  // ---- Loop A: both rows' pw/bs loads in one burst (2x MLP) ----
  float4 sc0[CHUNKS], sc1[CHUNKS];
#pragma unroll
  for (int j = 0; j < CHUNKS; ++j) {
    const int i = tid + j * BLK;
    const int c0 = i * 4;
    float4 s = zero4;
    if (c0 < L0) {
      const float4 w = pw40[i];
      const float4 b = bs40[i];
      s.x = fmaxf(w.x, 0.f) + BIAS_W * (MIN_BW + fmaxf(b.x, 0.f));
      s.y = fmaxf(w.y, 0.f) + BIAS_W * (MIN_BW + fmaxf(b.y, 0.f));
      s.z = fmaxf(w.z, 0.f) + BIAS_W * (MIN_BW + fmaxf(b.z, 0.f));
      s.w = fmaxf(w.w, 0.f) + BIAS_W * (MIN_BW + fmaxf(b.w, 0.f));
    }
    sc0[j] = s;
    float4 s2 = zero4;
    if (valid1 && c0 < L1) {
      const float4 w = pw41[i];
      const float4 b = bs41[i];
      s2.x = fmaxf(w.x, 0.f) + BIAS_W * (MIN_BW + fmaxf(b.x, 0.f));
      s2.y = fmaxf(w.y, 0.f) + BIAS_W * (MIN_BW + fmaxf(b.y, 0.f));
      s2.z = fmaxf(w.z, 0.f) + BIAS_W * (MIN_BW + fmaxf(b.z, 0.f));
      s2.w = fmaxf(w.w, 0.f) + BIAS_W * (MIN_BW + fmaxf(b.w, 0.f));
    }
    sc1[j] = s2;
  }

  // ---- Loop B: exact-L masking + histograms + prev/prefix + early stores ----
  float prefl0 = 0.0f, prefl1 = 0.0f;
#pragma unroll
  for (int j = 0; j < CHUNKS; ++j) {
    const int i = tid + j * BLK;
    const int c0 = i * 4;
    if (c0 >= L0) {
      sc0[j] = zero4;
      nt_store4(out40 + i, zero4);  // final value
    } else {
      float4 s = sc0[j];
      if (c0 + 3 >= L0) {
        if (c0 + 1 >= L0) s.y = 0.f;
        if (c0 + 2 >= L0) s.z = 0.f;
        if (c0 + 3 >= L0) s.w = 0.f;
        sc0[j] = s;
      }
      if (!ng0) {
        atomicAdd(&s_h0[min(NBINS - 1, (int)(s.x * binscale))], 1);
        if (c0 + 1 < L0) atomicAdd(&s_h0[min(NBINS - 1, (int)(s.y * binscale))], 1);
        if (c0 + 2 < L0) atomicAdd(&s_h0[min(NBINS - 1, (int)(s.z * binscale))], 1);
        if (c0 + 3 < L0) atomicAdd(&s_h0[min(NBINS - 1, (int)(s.w * binscale))], 1);
      }
    }
    if (c0 < vfL0) {
      const float4 t = pv40[i];
      if (c0 + 3 < vfL0) {
        prefl0 += t.x + t.y + t.z + t.w;
        nt_store4(out40 + i, t);  // final value
      } else {
        prefl0 += t.x + ((c0 + 1 < vfL0) ? t.y : 0.f) +
                  ((c0 + 2 < vfL0) ? t.z : 0.f) + ((c0 + 3 < vfL0) ? t.w : 0.f);
      }
    }
  }
  if (valid1) {
#pragma unroll
    for (int j = 0; j < CHUNKS; ++j) {
      const int i = tid + j * BLK;
      const int c0 = i * 4;
      if (c0 >= L1) {
        sc1[j] = zero4;
        nt_store4(out41 + i, zero4);
      } else {
        float4 s = sc1[j];
        if (c0 + 3 >= L1) {
          if (c0 + 1 >= L1) s.y = 0.f;
          if (c0 + 2 >= L1) s.z = 0.f;
          if (c0 + 3 >= L1) s.w = 0.f;
          sc1[j] = s;
        }
        if (!ng1) {
          atomicAdd(&s_h1[min(NBINS - 1, (int)(s.x * binscale))], 1);
          if (c0 + 1 < L1) atomicAdd(&s_h1[min(NBINS - 1, (int)(s.y * binscale))], 1);
          if (c0 + 2 < L1) atomicAdd(&s_h1[min(NBINS - 1, (int)(s.z * binscale))], 1);
          if (c0 + 3 < L1) atomicAdd(&s_h1[min(NBINS - 1, (int)(s.w * binscale))], 1);
        }
      }
      if (c0 < vfL1) {
        const float4 t = pv41[i];
        if (c0 + 3 < vfL1) {
          prefl1 += t.x + t.y + t.z + t.w;
          nt_store4(out41 + i, t);
        } else {
          prefl1 += t.x + ((c0 + 1 < vfL1) ? t.y : 0.f) +
                    ((c0 + 2 < vfL1) ? t.z : 0.f) + ((c0 + 3 < vfL1) ? t.w : 0.f);
        }
      }
    }
  }

  // ---- fused dual suffix-select (two interleaved scans, one barrier set) ----
  __syncthreads();  // A: both hists complete
  {
    const int g = 255 - tid;  // thread owns bins [4g, 4g+4), high->low tid
    const int4 h0 = reinterpret_cast<const int4*>(s_h0)[g];
    const int4 h1 = reinterpret_cast<const int4*>(s_h1)[g];
    const int v0 = h0.x + h0.y + h0.z + h0.w;
    const int v1 = h1.x + h1.y + h1.z + h1.w;
    int x0 = v0, x1 = v1;
#pragma unroll
    for (int o = 1; o < 64; o <<= 1) {
      const int y0 = __shfl_up(x0, o, 64);
      const int y1 = __shfl_up(x1, o, 64);
      if (lane >= o) { x0 += y0; x1 += y1; }
    }
    if (lane == 63) { s_w0[wid] = x0; s_w1[wid] = x1; }
    __syncthreads();  // B
    if (wid > 0) { x0 += s_w0[0]; x1 += s_w1[0]; }
    if (wid > 1) { x0 += s_w0[1]; x1 += s_w1[1]; }
    if (wid > 2) { x0 += s_w0[2]; x1 += s_w1[2]; }
    if (!ng0 && x0 >= kk0 && (x0 - v0) < kk0) {  // unique crossing thread row0
      int cum = x0 - v0;
      int bin;
      cum += h0.w;
      if (cum >= kk0) bin = g * 4 + 3;
      else {
        cum += h0.z;
        if (cum >= kk0) bin = g * 4 + 2;
        else {
          cum += h0.y;
          bin = (cum >= kk0) ? g * 4 + 1 : g * 4;
        }
      }
      s_bin0 = bin;
    }
    if (!ng1 && x1 >= kk1 && (x1 - v1) < kk1) {  // unique crossing thread row1
      int cum = x1 - v1;
      int bin;
      cum += h1.w;
      if (cum >= kk1) bin = g * 4 + 3;
      else {
        cum += h1.z;
        if (cum >= kk1) bin = g * 4 + 2;
        else {
          cum += h1.y;
          bin = (cum >= kk1) ? g * 4 + 1 : g * 4;
        }
      }
      s_bin1 = bin;
    }
  }
  __syncthreads();  // C
  // thr err <= HIV/1024 = 1.22e-3; damped by sigmoid(T=0.12) + renorm.
  const float thr0 = ng0 ? 0.0f : (float)s_bin0 * (HIV / (float)NBINS);
  const float thr1 = ng1 ? 0.0f : (float)s_bin1 * (HIV / (float)NBINS);

  // ---- gating + tail candidate sums ----
  const float inv_temp = 1.0f / TEMP;
  float tsl0 = 0.0f, tsl1 = 0.0f;
#pragma unroll
  for (int j = 0; j < CHUNKS; ++j) {
    const int c0 = (tid + j * BLK) * 4;
    if (c0 + 3 >= vfL0 && c0 < L0) {
      const float4 s = sc0[j];
      float4 sel;
      if (ng0) {
        sel = s;
      } else {
        sel.x = s.x * __builtin_amdgcn_rcpf(1.0f + __expf((thr0 - s.x) * inv_temp));
        sel.y = s.y * __builtin_amdgcn_rcpf(1.0f + __expf((thr0 - s.y) * inv_temp));
        sel.z = s.z * __builtin_amdgcn_rcpf(1.0f + __expf((thr0 - s.z) * inv_temp));
        sel.w = s.w * __builtin_amdgcn_rcpf(1.0f + __expf((thr0 - s.w) * inv_temp));
      }
      tsl0 += ((c0 >= vfL0 && c0 < L0) ? sel.x : 0.f) +
              ((c0 + 1 >= vfL0 && c0 + 1 < L0) ? sel.y : 0.f) +
              ((c0 + 2 >= vfL0 && c0 + 2 < L0) ? sel.z : 0.f) +
              ((c0 + 3 >= vfL0 && c0 + 3 < L0) ? sel.w : 0.f);
      sc0[j] = sel;
    }
  }
  if (valid1) {
#pragma unroll
    for (int j = 0; j < CHUNKS; ++j) {
      const int c0 = (tid + j * BLK) * 4;
      if (c0 + 3 >= vfL1 && c0 < L1) {
        const float4 s = sc1[j];
        float4 sel;
        if (ng1) {
          sel = s;
        } else {
          sel.x = s.x * __builtin_amdgcn_rcpf(1.0f + __expf((thr1 - s.x) * inv_temp));
          sel.y = s.y * __builtin_amdgcn_rcpf(1.0f + __expf((thr1 - s.y) * inv_temp));
          sel.z = s.z * __builtin_amdgcn_rcpf(1.0f + __expf((thr1 - s.z) * inv_temp));
          sel.w = s.w * __builtin_amdgcn_rcpf(1.0f + __expf((thr1 - s.w) * inv_temp));
        }
        tsl1 += ((c0 >= vfL1 && c0 < L1) ? sel.x : 0.f) +
                ((c0 + 1 >= vfL1 && c0 + 1 < L1) ? sel.y : 0.f) +
                ((c0 + 2 >= vfL1 && c0 + 2 < L1) ? sel.z : 0.f) +
                ((c0 + 3 >= vfL1 && c0 + 3 < L1) ? sel.w : 0.f);
        sc1[j] = sel;
      }
    }
  }

  // ---- combined block reduction of 4 partial sums ----
  {
    float a = prefl0, b = tsl0, c = prefl1, d = tsl1;
#pragma unroll
    for (int o = 32; o > 0; o >>= 1) {
      a += __shfl_down(a, o, 64);
      b += __shfl_down(b, o, 64);
      c += __shfl_down(c, o, 64);
      d += __shfl_down(d, o, 64);
    }
    if (lane == 0) {
      s_part[wid] = a;
      s_part[4 + wid] = b;
      s_part[8 + wid] = c;
      s_part[12 + wid] = d;
    }
  }
  __syncthreads();  // D
  const float prefix0 = s_part[0] + s_part[1] + s_part[2] + s_part[3];
  const float tcand0 = s_part[4] + s_part[5] + s_part[6] + s_part[7];
  const float prefix1 = s_part[8] + s_part[9] + s_part[10] + s_part[11];
  const float tcand1 = s_part[12] + s_part[13] + s_part[14] + s_part[15];

  const int tc0 = L0 - vfL0;
  const float scale0 =
      fmaxf(bud0 - prefix0, 0.0f) /
      fmaxf(tcand0 + (tc0 > 0 ? EPSF : 0.0f), EPSF);
  const float fb0 = (tc0 > 0) ? (EPSF / (float)tc0) : 0.0f;
  const int tc1 = L1 - vfL1;
  const float scale1 =
      fmaxf(bud1 - prefix1, 0.0f) /
      fmaxf(tcand1 + (tc1 > 0 ? EPSF : 0.0f), EPSF);
  const float fb1 = (tc1 > 0) ? (EPSF / (float)tc1) : 0.0f;

  // ---- write remaining chunks for both rows ----
#pragma unroll
  for (int j = 0; j < CHUNKS; ++j) {
    const int i = tid + j * BLK;
    const int c0 = i * 4;
    if (!(c0 + 3 < vfL0) && c0 < L0) {
      const float4 s = sc0[j];
      float4 o;
      if (c0 >= vfL0 && c0 + 3 < L0) {  // pure tail chunk
        o.x = (s.x + fb0) * scale0;
        o.y = (s.y + fb0) * scale0;
        o.z = (s.z + fb0) * scale0;
        o.w = (s.w + fb0) * scale0;
      } else {  // boundary chunk(s)
        const float4 p = (c0 < vfL0) ? pv40[i] : zero4;
        o.x = (c0 < vfL0) ? p.x : ((c0 < L0) ? (s.x + fb0) * scale0 : 0.f);
        o.y = (c0 + 1 < vfL0) ? p.y : ((c0 + 1 < L0) ? (s.y + fb0) * scale0 : 0.f);
        o.z = (c0 + 2 < vfL0) ? p.z : ((c0 + 2 < L0) ? (s.z + fb0) * scale0 : 0.f);
        o.w = (c0 + 3 < vfL0) ? p.w : ((c0 + 3 < L0) ? (s.w + fb0) * scale0 : 0.f);
      }
      nt_store4(out40 + i, o);
    }
  }
  if (valid1) {
#pragma unroll
    for (int j = 0; j < CHUNKS; ++j) {
      const int i = tid + j * BLK;
      const int c0 = i * 4;
      if (!(c0 + 3 < vfL1) && c0 < L1) {
        const float4 s = sc1[j];
        float4 o;
        if (c0 >= vfL1 && c0 + 3 < L1) {
          o.x = (s.x + fb1) * scale1;
          o.y = (s.y + fb1) * scale1;
          o.z = (s.z + fb1) * scale1;
          o.w = (s.w + fb1) * scale1;
        } else {
          const float4 p = (c0 < vfL1) ? pv41[i] : zero4;
          o.x = (c0 < vfL1) ? p.x : ((c0 < L1) ? (s.x + fb1) * scale1 : 0.f);
          o.y = (c0 + 1 < vfL1) ? p.y : ((c0 + 1 < L1) ? (s.y + fb1) * scale1 : 0.f);
          o.z = (c0 + 2 < vfL1) ? p.z : ((c0 + 2 < L1) ? (s.z + fb1) * scale1 : 0.f);
          o.w = (c0 + 3 < vfL1) ? p.w : ((c0 + 3 < L1) ? (s.w + fb1) * scale1 : 0.f);
        }
        nt_store4(out41 + i, o);
      }
    }
  }
}

extern "C" void kernel_launch(void* const* d_in, const int* in_sizes, int n_in,
                              void* d_out, int out_size, void* d_ws, size_t ws_size,
                              hipStream_t stream) {
  const float* pw = (const float*)d_in[0];
  const float* bs = (const float*)d_in[1];
  const float* msk = (const float*)d_in[2];
  const float* bud = (const float*)d_in[3];
  const float* prev = (const float*)d_in[4];
  const int* cf = (const int*)d_in[5];
  float* out = (float*)d_out;
  const int rows = out_size / UNITS;
  const int blocks = (rows + 1) / 2;
  srp_kernel<<<dim3(blocks), dim3(BLK), 0, stream>>>(pw, bs, msk, bud, prev, cf,
                                                     out, rows);
}

// Round 8
// 30.892 us; speedup vs baseline: 1.1650x; 1.1650x over previous
//
#include <hip/hip_runtime.h>
#include <math.h>

#define UNITS 4096
#define BLK 256
#define CHUNKS 4      // 256 threads * 4 chunks * 4 floats = 4096
#define NBINS 1024

typedef float f32x4 __attribute__((ext_vector_type(4)));

__device__ __forceinline__ void nt_store4(float4* p, float4 v) {
  __builtin_nontemporal_store(*reinterpret_cast<f32x4*>(&v),
                              reinterpret_cast<f32x4*>(p));
}

__global__ __launch_bounds__(BLK) void srp_kernel(
    const float* __restrict__ pw, const float* __restrict__ bs,
    const float* __restrict__ msk, const float* __restrict__ budget,
    const float* __restrict__ prev, const int* __restrict__ cf,
    float* __restrict__ out) {
  constexpr float TOPK_RATIO = 0.35f;
  constexpr float MIN_BW = 0.1f;
  constexpr float BIAS_W = 0.15f;
  constexpr float TEMP = 0.12f;
  constexpr float EPSF = 1e-6f;
  constexpr float HIV = 1.25f;  // scores <= 1.165 < 1.25
  const float binscale = (float)NBINS / HIV;

  __shared__ int s_h[NBINS];   // 4 KB block-shared histogram
  __shared__ int s_w[4];
  __shared__ int s_bin;
  __shared__ float s_part[8];  // [0..3]=prefl partials, [4..7]=tail partials

  const int tid = threadIdx.x;
  const int lane = tid & 63;
  const int wid = tid >> 6;
  const int row = blockIdx.x;
  const size_t base = (size_t)row * UNITS;

  reinterpret_cast<int4*>(s_h)[tid] = make_int4(0, 0, 0, 0);

  int vf = cf[row];
  const float bud = budget[row];

  // ---- L = prefix length of ones-mask: per-wave redundant 3-round narrow
  // ballot probe (no LDS broadcast, no barrier; ~1.3 KB traffic/row). ----
  int L;
  {
    bool t1 = (lane < 8) ? (msk[base + lane * 512 + 511] > 0.0f) : false;
    const int q1 = __popcll(__ballot(t1));
    if (q1 == 8) {
      L = 4096;
    } else {
      bool t2 = (lane < 8) ? (msk[base + q1 * 512 + lane * 64 + 63] > 0.0f) : false;
      const int q2 = __popcll(__ballot(t2));
      const int q0 = q1 * 512 + q2 * 64;
      const bool t3 = msk[base + q0 + lane] > 0.0f;
      L = q0 + __popcll(__ballot(t3));
    }
  }

  const float Lf = (float)L;
  float kf = fmaxf(1.0f, rintf(Lf * TOPK_RATIO));  // rintf == jnp.round (half-even)
  kf = fminf(kf, fmaxf(Lf, 1.0f));
  const int kk = (int)kf;
  const bool no_gate = (kf >= Lf);  // block-uniform

  vf = min(max(vf, 0), UNITS);
  const int vfL = min(vf, L);  // prefix region [0, vfL): out = prev

  const float4* pw4 = reinterpret_cast<const float4*>(pw + base);
  const float4* bs4 = reinterpret_cast<const float4*>(bs + base);
  const float4* pv4 = reinterpret_cast<const float4*>(prev + base);
  float4* out4 = reinterpret_cast<float4*>(out + base);
  const float4 zero4 = make_float4(0.f, 0.f, 0.f, 0.f);

  // ---- pass 1: scores->regs, histogram, prev/prefix sum, early stores ----
  float4 sc[CHUNKS];
  float prefl = 0.0f;
#pragma unroll
  for (int j = 0; j < CHUNKS; ++j) {
    const int i = tid + j * BLK;
    const int c0 = i * 4;
    float4 s = zero4;
    if (c0 < L) {
      const float4 w = pw4[i];
      const float4 b = bs4[i];
      s.x = fmaxf(w.x, 0.f) + BIAS_W * (MIN_BW + fmaxf(b.x, 0.f));
      s.y = fmaxf(w.y, 0.f) + BIAS_W * (MIN_BW + fmaxf(b.y, 0.f));
      s.z = fmaxf(w.z, 0.f) + BIAS_W * (MIN_BW + fmaxf(b.z, 0.f));
      s.w = fmaxf(w.w, 0.f) + BIAS_W * (MIN_BW + fmaxf(b.w, 0.f));
      if (c0 + 3 >= L) {  // L-boundary chunk: zero out-of-range comps
        if (c0 + 1 >= L) s.y = 0.f;
        if (c0 + 2 >= L) s.z = 0.f;
        if (c0 + 3 >= L) s.w = 0.f;
      }
      if (!no_gate) {
        atomicAdd(&s_h[min(NBINS - 1, (int)(s.x * binscale))], 1);
        if (c0 + 1 < L) atomicAdd(&s_h[min(NBINS - 1, (int)(s.y * binscale))], 1);
        if (c0 + 2 < L) atomicAdd(&s_h[min(NBINS - 1, (int)(s.z * binscale))], 1);
        if (c0 + 3 < L) atomicAdd(&s_h[min(NBINS - 1, (int)(s.w * binscale))], 1);
      }
    } else {
      nt_store4(out4 + i, zero4);  // final value, store now
    }
    sc[j] = s;
    if (c0 < vfL) {
      const float4 t = pv4[i];
      if (c0 + 3 < vfL) {
        prefl += t.x + t.y + t.z + t.w;
        nt_store4(out4 + i, t);  // final value, store now
      } else {
        prefl += t.x + ((c0 + 1 < vfL) ? t.y : 0.f) +
                 ((c0 + 2 < vfL) ? t.z : 0.f) + ((c0 + 3 < vfL) ? t.w : 0.f);
      }
    }
  }

  // ---- prefix reduce shares barrier A with histogram completion ----
  {
    float a = prefl;
#pragma unroll
    for (int o = 32; o > 0; o >>= 1) a += __shfl_down(a, o, 64);
    if (lane == 0) s_part[wid] = a;
  }
  __syncthreads();  // A: hist + prefl partials ready
  const float prefix_sum = s_part[0] + s_part[1] + s_part[2] + s_part[3];
  const float remaining = fmaxf(bud - prefix_sum, 0.0f);
  // remaining==0 -> tail_values = cand*(0/total) = 0 EXACTLY in the reference
  // -> all tail outputs are 0; select/gate/tail-reduce are dead code.
  const bool do_tail = (remaining > 0.0f);          // block-uniform
  const bool need_sel = (!no_gate) && do_tail;      // block-uniform

  // ---- 1024-bin suffix select (only when the threshold matters) ----
  float thr = 0.0f;
  if (need_sel) {
    const int g = 255 - tid;  // thread owns 4 bins [4g, 4g+4), high->low tid
    const int4 hv = reinterpret_cast<const int4*>(s_h)[g];
    const int v = hv.x + hv.y + hv.z + hv.w;
    int x = v;  // inclusive scan over threads == suffix sum over bins
#pragma unroll
    for (int o = 1; o < 64; o <<= 1) {
      int y = __shfl_up(x, o, 64);
      if (lane >= o) x += y;
    }
    if (lane == 63) s_w[wid] = x;
    __syncthreads();  // B
    if (wid > 0) x += s_w[0];
    if (wid > 1) x += s_w[1];
    if (wid > 2) x += s_w[2];
    if (x >= kk && (x - v) < kk) {  // unique crossing thread
      int cum = x - v;
      int bin;
      cum += hv.w;
      if (cum >= kk) bin = g * 4 + 3;
      else {
        cum += hv.z;
        if (cum >= kk) bin = g * 4 + 2;
        else {
          cum += hv.y;
          bin = (cum >= kk) ? g * 4 + 1 : g * 4;
        }
      }
      s_bin = bin;
    }
    __syncthreads();  // C
    // thr err <= HIV/1024 = 1.22e-3; damped by sigmoid(T=0.12) + renorm.
    thr = (float)s_bin * (HIV / (float)NBINS);
  }

  // ---- gating + tail reduce + write params ----
  float scale = 0.0f, fb = 0.0f;
  if (do_tail) {
    const float inv_temp = 1.0f / TEMP;
    float tsl = 0.0f;
#pragma unroll
    for (int j = 0; j < CHUNKS; ++j) {
      const int c0 = (tid + j * BLK) * 4;
      if (c0 + 3 >= vfL && c0 < L) {  // intersects tail [vfL, L)
        const float4 s = sc[j];
        float4 sel;
        if (no_gate) {
          sel = s;
        } else {
          sel.x = s.x * __builtin_amdgcn_rcpf(1.0f + __expf((thr - s.x) * inv_temp));
          sel.y = s.y * __builtin_amdgcn_rcpf(1.0f + __expf((thr - s.y) * inv_temp));
          sel.z = s.z * __builtin_amdgcn_rcpf(1.0f + __expf((thr - s.z) * inv_temp));
          sel.w = s.w * __builtin_amdgcn_rcpf(1.0f + __expf((thr - s.w) * inv_temp));
        }
        tsl += ((c0 >= vfL && c0 < L) ? sel.x : 0.f) +
               ((c0 + 1 >= vfL && c0 + 1 < L) ? sel.y : 0.f) +
               ((c0 + 2 >= vfL && c0 + 2 < L) ? sel.z : 0.f) +
               ((c0 + 3 >= vfL && c0 + 3 < L) ? sel.w : 0.f);
        sc[j] = sel;
      }
    }
    {
      float b = tsl;
#pragma unroll
      for (int o = 32; o > 0; o >>= 1) b += __shfl_down(b, o, 64);
      if (lane == 0) s_part[4 + wid] = b;
    }
    __syncthreads();  // D
    const float tail_cand = s_part[4] + s_part[5] + s_part[6] + s_part[7];
    const int tc = L - vfL;
    const float cand_sum = tail_cand + (tc > 0 ? EPSF : 0.0f);
    scale = remaining / fmaxf(cand_sum, EPSF);
    fb = (tc > 0) ? (EPSF / (float)tc) : 0.0f;
  }
  // !do_tail: scale=0, fb=0 -> generic write emits exact zeros for tail.

  // ---- write remaining chunks (tail + at most 2 boundary chunks) ----
#pragma unroll
  for (int j = 0; j < CHUNKS; ++j) {
    const int i = tid + j * BLK;
    const int c0 = i * 4;
    if (c0 + 3 < vfL) continue;  // stored in pass 1
    if (c0 >= L) continue;       // stored in pass 1
    const float4 s = sc[j];
    float4 o;
    if (c0 >= vfL && c0 + 3 < L) {  // pure tail chunk
      o.x = (s.x + fb) * scale;
      o.y = (s.y + fb) * scale;
      o.z = (s.z + fb) * scale;
      o.w = (s.w + fb) * scale;
    } else {  // boundary chunk(s): per-component; re-read prev if needed
      const float4 p = (c0 < vfL) ? pv4[i] : zero4;
      o.x = (c0 < vfL) ? p.x : ((c0 < L) ? (s.x + fb) * scale : 0.f);
      o.y = (c0 + 1 < vfL) ? p.y : ((c0 + 1 < L) ? (s.y + fb) * scale : 0.f);
      o.z = (c0 + 2 < vfL) ? p.z : ((c0 + 2 < L) ? (s.z + fb) * scale : 0.f);
      o.w = (c0 + 3 < vfL) ? p.w : ((c0 + 3 < L) ? (s.w + fb) * scale : 0.f);
    }
    nt_store4(out4 + i, o);
  }
}

extern "C" void kernel_launch(void* const* d_in, const int* in_sizes, int n_in,
                              void* d_out, int out_size, void* d_ws, size_t ws_size,
                              hipStream_t stream) {
  const float* pw = (const float*)d_in[0];
  const float* bs = (const float*)d_in[1];
  const float* msk = (const float*)d_in[2];
  const float* bud = (const float*)d_in[3];
  const float* prev = (const float*)d_in[4];
  const int* cf = (const int*)d_in[5];
  float* out = (float*)d_out;
  const int rows = out_size / UNITS;
  srp_kernel<<<dim3(rows), dim3(BLK), 0, stream>>>(pw, bs, msk, bud, prev, cf, out);
}